// Round 1
// baseline (4359.026 us; speedup 1.0000x reference)
//
#include <hip/hip_runtime.h>
#include <math.h>

#define NNODES 50000
#define NEDGES 800000
#define FDIM 128

__device__ __forceinline__ float gelu_erf(float x){
    return 0.5f * x * (1.0f + erff(x * 0.70710678118654752f));
}

// ---------------- degree / norm ----------------
__global__ void k_deg_init(float* __restrict__ deg){
    int i = blockIdx.x*blockDim.x + threadIdx.x;
    if (i < NNODES) deg[i] = 1.0f;   // self-loop contributes 1
}
__global__ void k_deg_accum(const int* __restrict__ ei, float* __restrict__ deg){
    int e = blockIdx.x*blockDim.x + threadIdx.x;
    if (e < NEDGES){
        int c = ei[NEDGES + e];      // col
        atomicAdd(&deg[c], 1.0f);
    }
}
__global__ void k_dinv(float* __restrict__ deg){
    int i = blockIdx.x*blockDim.x + threadIdx.x;
    if (i < NNODES) deg[i] = rsqrtf(deg[i]);
}

// ---------------- feature importance ----------------
__global__ void k_featimp(const float* __restrict__ x, const float* __restrict__ imp,
                          float* __restrict__ h){
    int g = blockIdx.x*blockDim.x + threadIdx.x;   // over N*32 float4s
    if (g < NNODES*32){
        int f4 = g & 31;
        float4 xv = ((const float4*)x)[g];
        float4 iv = ((const float4*)imp)[f4];
        float4 r; r.x=xv.x*iv.x; r.y=xv.y*iv.y; r.z=xv.z*iv.z; r.w=xv.w*iv.w;
        ((float4*)h)[g] = r;
    }
}

// ---------------- GEMM [nrows,128] x [128,128] ----------------
// Block: 256 threads, tile 32 rows x 128 cols, K tiled by 32.
// Thread (tx=t&31, ty=t>>5) computes 4 rows x 4 cols.
__global__ __launch_bounds__(256) void k_gemm128(const float* __restrict__ A,
                                                 const float* __restrict__ W,
                                                 const float* __restrict__ bias,
                                                 int fuse_gelu,
                                                 float* __restrict__ Y){
    __shared__ float Ht[32][33];
    __shared__ float Wt[32][128];
    int row0 = blockIdx.x * 32;
    int t = threadIdx.x;
    int tx = t & 31;
    int ty = t >> 5;
    int j0 = tx * 4;
    int r0 = ty * 4;
    float acc[4][4] = {{0.f,0.f,0.f,0.f},{0.f,0.f,0.f,0.f},{0.f,0.f,0.f,0.f},{0.f,0.f,0.f,0.f}};

    for (int k0 = 0; k0 < 128; k0 += 32){
        #pragma unroll
        for (int p=0;p<4;p++){
            int lin = p*256 + t;
            int r = lin >> 5, c = lin & 31;
            int gr = row0 + r;
            Ht[r][c] = (gr < NNODES) ? A[gr*FDIM + k0 + c] : 0.0f;
        }
        #pragma unroll
        for (int p=0;p<4;p++){
            int lin = p*256 + t;
            int kk = lin >> 5, jc = (lin & 31) * 4;
            float4 wv = *(const float4*)&W[(k0+kk)*FDIM + jc];
            Wt[kk][jc+0]=wv.x; Wt[kk][jc+1]=wv.y; Wt[kk][jc+2]=wv.z; Wt[kk][jc+3]=wv.w;
        }
        __syncthreads();
        #pragma unroll
        for (int k=0;k<32;k++){
            float4 wv = *(const float4*)&Wt[k][j0];
            float h0v = Ht[r0+0][k];
            float h1v = Ht[r0+1][k];
            float h2v = Ht[r0+2][k];
            float h3v = Ht[r0+3][k];
            acc[0][0] = fmaf(h0v, wv.x, acc[0][0]);
            acc[0][1] = fmaf(h0v, wv.y, acc[0][1]);
            acc[0][2] = fmaf(h0v, wv.z, acc[0][2]);
            acc[0][3] = fmaf(h0v, wv.w, acc[0][3]);
            acc[1][0] = fmaf(h1v, wv.x, acc[1][0]);
            acc[1][1] = fmaf(h1v, wv.y, acc[1][1]);
            acc[1][2] = fmaf(h1v, wv.z, acc[1][2]);
            acc[1][3] = fmaf(h1v, wv.w, acc[1][3]);
            acc[2][0] = fmaf(h2v, wv.x, acc[2][0]);
            acc[2][1] = fmaf(h2v, wv.y, acc[2][1]);
            acc[2][2] = fmaf(h2v, wv.z, acc[2][2]);
            acc[2][3] = fmaf(h2v, wv.w, acc[2][3]);
            acc[3][0] = fmaf(h3v, wv.x, acc[3][0]);
            acc[3][1] = fmaf(h3v, wv.y, acc[3][1]);
            acc[3][2] = fmaf(h3v, wv.z, acc[3][2]);
            acc[3][3] = fmaf(h3v, wv.w, acc[3][3]);
        }
        __syncthreads();
    }
    float4 bv = make_float4(0.f,0.f,0.f,0.f);
    if (fuse_gelu) bv = *(const float4*)&bias[j0];
    #pragma unroll
    for (int rr=0; rr<4; rr++){
        int gr = row0 + r0 + rr;
        if (gr < NNODES){
            float4 v;
            v.x = acc[rr][0]; v.y = acc[rr][1]; v.z = acc[rr][2]; v.w = acc[rr][3];
            if (fuse_gelu){
                v.x = gelu_erf(v.x + bv.x);
                v.y = gelu_erf(v.y + bv.y);
                v.z = gelu_erf(v.z + bv.z);
                v.w = gelu_erf(v.w + bv.w);
            }
            *(float4*)&Y[gr*FDIM + j0] = v;
        }
    }
}

// ---------------- self-loop init of aggregator ----------------
__global__ void k_selfloop(const float* __restrict__ Y, const float* __restrict__ dinv,
                           float* __restrict__ agg){
    int g = blockIdx.x*blockDim.x + threadIdx.x;   // N*32 float4s
    if (g < NNODES*32){
        int i = g >> 5;
        float s = dinv[i]; s = s*s;
        float4 yv = ((const float4*)Y)[g];
        float4 r; r.x=s*yv.x; r.y=s*yv.y; r.z=s*yv.z; r.w=s*yv.w;
        ((float4*)agg)[g] = r;
    }
}

// ---------------- edge scatter-add ----------------
// 32 threads per edge, each handles 4 consecutive features.
__global__ void k_scatter(const float* __restrict__ Y, const float* __restrict__ dinv,
                          const int* __restrict__ ei, float* __restrict__ agg){
    int g = blockIdx.x*blockDim.x + threadIdx.x;   // E*32
    if (g < NEDGES*32){
        int e  = g >> 5;
        int f4 = g & 31;
        int r = ei[e];
        int c = ei[NEDGES + e];
        float w = dinv[r] * dinv[c];
        float4 yv = *(const float4*)&Y[r*FDIM + f4*4];
        float* dst = &agg[c*FDIM + f4*4];
        atomicAdd(dst+0, w*yv.x);
        atomicAdd(dst+1, w*yv.y);
        atomicAdd(dst+2, w*yv.z);
        atomicAdd(dst+3, w*yv.w);
    }
}

// ---------------- bias + gelu ----------------
__global__ void k_bias_gelu(const float* __restrict__ agg, const float* __restrict__ b,
                            float* __restrict__ h){
    int g = blockIdx.x*blockDim.x + threadIdx.x;   // N*32 float4s
    if (g < NNODES*32){
        int f4 = g & 31;
        float4 bv = ((const float4*)b)[f4];
        float4 v = ((const float4*)agg)[g];
        v.x = gelu_erf(v.x + bv.x);
        v.y = gelu_erf(v.y + bv.y);
        v.z = gelu_erf(v.z + bv.z);
        v.w = gelu_erf(v.w + bv.w);
        ((float4*)h)[g] = v;
    }
}

// ---------------- final GEMM [nrows,128] x [128,16] + bias ----------------
__global__ __launch_bounds__(256) void k_gemm16(const float* __restrict__ A,
                                                const float* __restrict__ W,
                                                const float* __restrict__ bias,
                                                float* __restrict__ out){
    __shared__ float Hs[16][132];
    __shared__ float Ws2[128][16];
    int row0 = blockIdx.x * 16;
    int t = threadIdx.x;
    #pragma unroll
    for (int p=0;p<8;p++){
        int lin = p*256 + t;
        int r = lin >> 7, c = lin & 127;
        Hs[r][c] = A[(row0+r)*FDIM + c];
    }
    #pragma unroll
    for (int p=0;p<8;p++){
        int lin = p*256 + t;
        Ws2[lin>>4][lin&15] = W[lin];
    }
    __syncthreads();
    int il = t >> 4, j = t & 15;
    float acc = bias[j];
    #pragma unroll
    for (int k=0;k<FDIM;k++) acc = fmaf(Hs[il][k], Ws2[k][j], acc);
    out[(row0+il)*16 + j] = acc;
}

extern "C" void kernel_launch(void* const* d_in, const int* in_sizes, int n_in,
                              void* d_out, int out_size, void* d_ws, size_t ws_size,
                              hipStream_t stream) {
    const float* x    = (const float*)d_in[0];
    const int*   ei   = (const int*)d_in[1];
    const float* imp  = (const float*)d_in[2];
    const float* W1   = (const float*)d_in[3];
    const float* b1   = (const float*)d_in[4];
    const float* W2   = (const float*)d_in[5];
    const float* b2   = (const float*)d_in[6];
    const float* W3   = (const float*)d_in[7];
    const float* b3   = (const float*)d_in[8];
    const float* lw1  = (const float*)d_in[9];
    const float* lb1  = (const float*)d_in[10];
    const float* lw2  = (const float*)d_in[11];
    const float* lb2  = (const float*)d_in[12];
    float* out = (float*)d_out;

    float* ws   = (float*)d_ws;
    float* dinv = ws;                                   // N floats (deg -> dinv in place)
    float* bufH = ws + 65536;                           // N*128
    float* bufY = bufH + (size_t)NNODES*FDIM;           // N*128
    float* bufG = bufY + (size_t)NNODES*FDIM;           // N*128

    dim3 B(256);
    // degrees -> dinv
    k_deg_init <<<(NNODES+255)/256, B, 0, stream>>>(dinv);
    k_deg_accum<<<(NEDGES+255)/256, B, 0, stream>>>(ei, dinv);
    k_dinv     <<<(NNODES+255)/256, B, 0, stream>>>(dinv);
    // h0 = x * importance
    k_featimp  <<<(NNODES*32+255)/256, B, 0, stream>>>(x, imp, bufH);

    const float* Wl[3] = {W1, W2, W3};
    const float* bl[3] = {b1, b2, b3};
    for (int l = 0; l < 3; l++){
        k_gemm128 <<<(NNODES+31)/32, B, 0, stream>>>(bufH, Wl[l], nullptr, 0, bufY);
        k_selfloop<<<(NNODES*32+255)/256, B, 0, stream>>>(bufY, dinv, bufG);
        k_scatter <<<(NEDGES*32+255)/256, B, 0, stream>>>(bufY, dinv, ei, bufG);
        k_bias_gelu<<<(NNODES*32+255)/256, B, 0, stream>>>(bufG, bl[l], bufH);
    }
    // h = gelu(h @ lw1 + lb1)
    k_gemm128<<<(NNODES+31)/32, B, 0, stream>>>(bufH, lw1, lb1, 1, bufY);
    // out = h @ lw2 + lb2
    k_gemm16 <<<NNODES/16, B, 0, stream>>>(bufY, lw2, lb2, out);
}

// Round 2
// 524.198 us; speedup vs baseline: 8.3156x; 8.3156x over previous
//
#include <hip/hip_runtime.h>
#include <math.h>

#define NNODES 50000
#define NEDGES 800000
#define FDIM 128
#define NBLK_SCAN 196   // ceil(50000/256)

__device__ __forceinline__ float gelu_erf(float x){
    return 0.5f * x * (1.0f + erff(x * 0.70710678118654752f));
}

// ---------------- CSR build ----------------
__global__ void k_zero_cnt(int* __restrict__ cnt){
    int i = blockIdx.x*blockDim.x + threadIdx.x;
    if (i < NNODES) cnt[i] = 0;
}
__global__ void k_hist(const int* __restrict__ ei, int* __restrict__ cnt){
    int e = blockIdx.x*blockDim.x + threadIdx.x;
    if (e < NEDGES) atomicAdd(&cnt[ei[NEDGES + e]], 1);
}
__global__ void k_dinv(const int* __restrict__ cnt, float* __restrict__ dinv){
    int i = blockIdx.x*blockDim.x + threadIdx.x;
    if (i < NNODES) dinv[i] = rsqrtf((float)(cnt[i] + 1));   // +1 self loop
}
__global__ __launch_bounds__(256) void k_blocksum(const int* __restrict__ cnt, int* __restrict__ bsum){
    __shared__ int sm[256];
    int t = threadIdx.x;
    int i = blockIdx.x*256 + t;
    sm[t] = (i < NNODES) ? cnt[i] : 0;
    __syncthreads();
    for (int off = 128; off > 0; off >>= 1){
        if (t < off) sm[t] += sm[t+off];
        __syncthreads();
    }
    if (t == 0) bsum[blockIdx.x] = sm[0];
}
__global__ __launch_bounds__(256) void k_scanblocks(int* __restrict__ bsum){
    __shared__ int sm[256];
    int t = threadIdx.x;
    int v = (t < NBLK_SCAN) ? bsum[t] : 0;
    sm[t] = v;
    __syncthreads();
    for (int off = 1; off < 256; off <<= 1){
        int tv = (t >= off) ? sm[t-off] : 0;
        __syncthreads();
        sm[t] += tv;
        __syncthreads();
    }
    if (t < NBLK_SCAN) bsum[t] = sm[t] - v;   // exclusive
}
__global__ __launch_bounds__(256) void k_scanfinal(const int* __restrict__ cnt,
                                                   const int* __restrict__ bsum,
                                                   int* __restrict__ offs,
                                                   int* __restrict__ cursor){
    __shared__ int sm[256];
    int t = threadIdx.x;
    int i = blockIdx.x*256 + t;
    int v = (i < NNODES) ? cnt[i] : 0;
    sm[t] = v;
    __syncthreads();
    for (int off = 1; off < 256; off <<= 1){
        int tv = (t >= off) ? sm[t-off] : 0;
        __syncthreads();
        sm[t] += tv;
        __syncthreads();
    }
    int excl = sm[t] - v + bsum[blockIdx.x];
    if (i < NNODES){ offs[i] = excl; cursor[i] = excl; }
    if (i == 0) offs[NNODES] = NEDGES;
}
__global__ void k_fill(const int* __restrict__ ei, const float* __restrict__ dinv,
                       int* __restrict__ cursor, int2* __restrict__ csr){
    int e = blockIdx.x*blockDim.x + threadIdx.x;
    if (e < NEDGES){
        int r = ei[e];
        int c = ei[NEDGES + e];
        int pos = atomicAdd(&cursor[c], 1);
        float w = dinv[r]*dinv[c];
        csr[pos] = make_int2(r, __float_as_int(w));
    }
}

// ---------------- feature importance ----------------
__global__ void k_featimp(const float* __restrict__ x, const float* __restrict__ imp,
                          float* __restrict__ h){
    int g = blockIdx.x*blockDim.x + threadIdx.x;   // over N*32 float4s
    if (g < NNODES*32){
        int f4 = g & 31;
        float4 xv = ((const float4*)x)[g];
        float4 iv = ((const float4*)imp)[f4];
        float4 r; r.x=xv.x*iv.x; r.y=xv.y*iv.y; r.z=xv.z*iv.z; r.w=xv.w*iv.w;
        ((float4*)h)[g] = r;
    }
}

// ---------------- GEMM [nrows,128] x [128,128] ----------------
__global__ __launch_bounds__(256) void k_gemm128(const float* __restrict__ A,
                                                 const float* __restrict__ W,
                                                 const float* __restrict__ bias,
                                                 int fuse_gelu,
                                                 float* __restrict__ Y){
    __shared__ float Ht[32][33];
    __shared__ float Wt[32][128];
    int row0 = blockIdx.x * 32;
    int t = threadIdx.x;
    int tx = t & 31;
    int ty = t >> 5;
    int j0 = tx * 4;
    int r0 = ty * 4;
    float acc[4][4] = {{0.f,0.f,0.f,0.f},{0.f,0.f,0.f,0.f},{0.f,0.f,0.f,0.f},{0.f,0.f,0.f,0.f}};

    for (int k0 = 0; k0 < 128; k0 += 32){
        #pragma unroll
        for (int p=0;p<4;p++){
            int lin = p*256 + t;
            int r = lin >> 5, c = lin & 31;
            int gr = row0 + r;
            Ht[r][c] = (gr < NNODES) ? A[gr*FDIM + k0 + c] : 0.0f;
        }
        #pragma unroll
        for (int p=0;p<4;p++){
            int lin = p*256 + t;
            int kk = lin >> 5, jc = (lin & 31) * 4;
            float4 wv = *(const float4*)&W[(k0+kk)*FDIM + jc];
            Wt[kk][jc+0]=wv.x; Wt[kk][jc+1]=wv.y; Wt[kk][jc+2]=wv.z; Wt[kk][jc+3]=wv.w;
        }
        __syncthreads();
        #pragma unroll
        for (int k=0;k<32;k++){
            float4 wv = *(const float4*)&Wt[k][j0];
            float h0v = Ht[r0+0][k];
            float h1v = Ht[r0+1][k];
            float h2v = Ht[r0+2][k];
            float h3v = Ht[r0+3][k];
            acc[0][0] = fmaf(h0v, wv.x, acc[0][0]);
            acc[0][1] = fmaf(h0v, wv.y, acc[0][1]);
            acc[0][2] = fmaf(h0v, wv.z, acc[0][2]);
            acc[0][3] = fmaf(h0v, wv.w, acc[0][3]);
            acc[1][0] = fmaf(h1v, wv.x, acc[1][0]);
            acc[1][1] = fmaf(h1v, wv.y, acc[1][1]);
            acc[1][2] = fmaf(h1v, wv.z, acc[1][2]);
            acc[1][3] = fmaf(h1v, wv.w, acc[1][3]);
            acc[2][0] = fmaf(h2v, wv.x, acc[2][0]);
            acc[2][1] = fmaf(h2v, wv.y, acc[2][1]);
            acc[2][2] = fmaf(h2v, wv.z, acc[2][2]);
            acc[2][3] = fmaf(h2v, wv.w, acc[2][3]);
            acc[3][0] = fmaf(h3v, wv.x, acc[3][0]);
            acc[3][1] = fmaf(h3v, wv.y, acc[3][1]);
            acc[3][2] = fmaf(h3v, wv.z, acc[3][2]);
            acc[3][3] = fmaf(h3v, wv.w, acc[3][3]);
        }
        __syncthreads();
    }
    float4 bv = make_float4(0.f,0.f,0.f,0.f);
    if (fuse_gelu) bv = *(const float4*)&bias[j0];
    #pragma unroll
    for (int rr=0; rr<4; rr++){
        int gr = row0 + r0 + rr;
        if (gr < NNODES){
            float4 v;
            v.x = acc[rr][0]; v.y = acc[rr][1]; v.z = acc[rr][2]; v.w = acc[rr][3];
            if (fuse_gelu){
                v.x = gelu_erf(v.x + bv.x);
                v.y = gelu_erf(v.y + bv.y);
                v.z = gelu_erf(v.z + bv.z);
                v.w = gelu_erf(v.w + bv.w);
            }
            *(float4*)&Y[gr*FDIM + j0] = v;
        }
    }
}

// ---------------- fused aggregation: self-loop + gather + bias + gelu ----------------
// One wave (64 lanes) per node; lane handles 2 features (float2). 4 nodes/block.
__global__ __launch_bounds__(256) void k_aggregate(const float* __restrict__ Y,
                                                   const float* __restrict__ dinv,
                                                   const int* __restrict__ offs,
                                                   const int2* __restrict__ csr,
                                                   const float* __restrict__ bias,
                                                   float* __restrict__ Hout){
    int node = blockIdx.x*4 + (threadIdx.x >> 6);
    int lane = threadIdx.x & 63;
    const float2* Y2 = (const float2*)Y;
    float di = dinv[node];
    float2 y0 = Y2[node*64 + lane];
    float2 acc;
    acc.x = di*di*y0.x;
    acc.y = di*di*y0.y;
    int e0 = offs[node], e1 = offs[node+1];
    int e = e0;
    for (; e + 1 < e1; e += 2){
        int2 p0 = csr[e];
        int2 p1 = csr[e+1];
        float w0 = __int_as_float(p0.y);
        float w1 = __int_as_float(p1.y);
        float2 a0 = Y2[p0.x*64 + lane];
        float2 a1 = Y2[p1.x*64 + lane];
        acc.x = fmaf(w0, a0.x, acc.x);
        acc.y = fmaf(w0, a0.y, acc.y);
        acc.x = fmaf(w1, a1.x, acc.x);
        acc.y = fmaf(w1, a1.y, acc.y);
    }
    if (e < e1){
        int2 p = csr[e];
        float w = __int_as_float(p.y);
        float2 a = Y2[p.x*64 + lane];
        acc.x = fmaf(w, a.x, acc.x);
        acc.y = fmaf(w, a.y, acc.y);
    }
    float2 bv = ((const float2*)bias)[lane];
    acc.x = gelu_erf(acc.x + bv.x);
    acc.y = gelu_erf(acc.y + bv.y);
    ((float2*)Hout)[node*64 + lane] = acc;
}

// ---------------- final GEMM [nrows,128] x [128,16] + bias ----------------
__global__ __launch_bounds__(256) void k_gemm16(const float* __restrict__ A,
                                                const float* __restrict__ W,
                                                const float* __restrict__ bias,
                                                float* __restrict__ out){
    __shared__ float Hs[16][132];
    __shared__ float Ws2[128][16];
    int row0 = blockIdx.x * 16;
    int t = threadIdx.x;
    #pragma unroll
    for (int p=0;p<8;p++){
        int lin = p*256 + t;
        int r = lin >> 7, c = lin & 127;
        Hs[r][c] = A[(row0+r)*FDIM + c];
    }
    #pragma unroll
    for (int p=0;p<8;p++){
        int lin = p*256 + t;
        Ws2[lin>>4][lin&15] = W[lin];
    }
    __syncthreads();
    int il = t >> 4, j = t & 15;
    float acc = bias[j];
    #pragma unroll
    for (int k=0;k<FDIM;k++) acc = fmaf(Hs[il][k], Ws2[k][j], acc);
    out[(row0+il)*16 + j] = acc;
}

extern "C" void kernel_launch(void* const* d_in, const int* in_sizes, int n_in,
                              void* d_out, int out_size, void* d_ws, size_t ws_size,
                              hipStream_t stream) {
    const float* x    = (const float*)d_in[0];
    const int*   ei   = (const int*)d_in[1];
    const float* imp  = (const float*)d_in[2];
    const float* W1   = (const float*)d_in[3];
    const float* b1   = (const float*)d_in[4];
    const float* W2   = (const float*)d_in[5];
    const float* b2   = (const float*)d_in[6];
    const float* W3   = (const float*)d_in[7];
    const float* b3   = (const float*)d_in[8];
    const float* lw1  = (const float*)d_in[9];
    const float* lb1  = (const float*)d_in[10];
    const float* lw2  = (const float*)d_in[11];
    const float* lb2  = (const float*)d_in[12];
    float* out = (float*)d_out;

    // workspace layout (units of 4 bytes)
    int*   cnt    = (int*)d_ws;                         // [0,      50000)
    int*   offs   = (int*)d_ws + 50176;                 // 50001
    int*   cursor = (int*)d_ws + 100480;                // 50000
    int*   bsum   = (int*)d_ws + 150528;                // 256
    float* dinv   = (float*)d_ws + 150784;              // 50000
    int2*  csr    = (int2*)((int*)d_ws + 200960);       // 800000 int2 (byte off 803840, %8==0)
    float* bufH   = (float*)d_ws + 1800960;             // N*128
    float* bufY   = (float*)d_ws + 8200960;             // N*128

    dim3 B(256);
    // ---- CSR build ----
    k_zero_cnt  <<<NBLK_SCAN, B, 0, stream>>>(cnt);
    k_hist      <<<(NEDGES+255)/256, B, 0, stream>>>(ei, cnt);
    k_dinv      <<<NBLK_SCAN, B, 0, stream>>>(cnt, dinv);
    k_blocksum  <<<NBLK_SCAN, B, 0, stream>>>(cnt, bsum);
    k_scanblocks<<<1, B, 0, stream>>>(bsum);
    k_scanfinal <<<NBLK_SCAN, B, 0, stream>>>(cnt, bsum, offs, cursor);
    k_fill      <<<(NEDGES+255)/256, B, 0, stream>>>(ei, dinv, cursor, csr);

    // ---- h0 = x * importance ----
    k_featimp<<<(NNODES*32+255)/256, B, 0, stream>>>(x, imp, bufH);

    const float* Wl[3] = {W1, W2, W3};
    const float* bl[3] = {b1, b2, b3};
    for (int l = 0; l < 3; l++){
        k_gemm128  <<<(NNODES+31)/32, B, 0, stream>>>(bufH, Wl[l], nullptr, 0, bufY);
        k_aggregate<<<(NNODES+3)/4, B, 0, stream>>>(bufY, dinv, offs, csr, bl[l], bufH);
    }
    // h = gelu(h @ lw1 + lb1)
    k_gemm128<<<(NNODES+31)/32, B, 0, stream>>>(bufH, lw1, lb1, 1, bufY);
    // out = h @ lw2 + lb2
    k_gemm16 <<<NNODES/16, B, 0, stream>>>(bufY, lw2, lb2, out);
}

// Round 3
// 499.795 us; speedup vs baseline: 8.7216x; 1.0488x over previous
//
#include <hip/hip_runtime.h>
#include <math.h>

#define NNODES 50000
#define NEDGES 800000
#define FDIM 128
#define NBLK_SCAN 196   // ceil(50000/256)

__device__ __forceinline__ float gelu_erf(float x){
    return 0.5f * x * (1.0f + erff(x * 0.70710678118654752f));
}

// ---------------- CSR build ----------------
__global__ void k_zero_cnt(int* __restrict__ cnt){
    int i = blockIdx.x*blockDim.x + threadIdx.x;
    if (i < NNODES) cnt[i] = 0;
}
__global__ void k_hist(const int* __restrict__ ei, int* __restrict__ cnt){
    int e = blockIdx.x*blockDim.x + threadIdx.x;
    if (e < NEDGES) atomicAdd(&cnt[ei[NEDGES + e]], 1);
}
__global__ __launch_bounds__(256) void k_blocksum(const int* __restrict__ cnt, int* __restrict__ bsum){
    __shared__ int sm[256];
    int t = threadIdx.x;
    int i = blockIdx.x*256 + t;
    sm[t] = (i < NNODES) ? cnt[i] : 0;
    __syncthreads();
    for (int off = 128; off > 0; off >>= 1){
        if (t < off) sm[t] += sm[t+off];
        __syncthreads();
    }
    if (t == 0) bsum[blockIdx.x] = sm[0];
}
__global__ __launch_bounds__(256) void k_scanblocks(int* __restrict__ bsum){
    __shared__ int sm[256];
    int t = threadIdx.x;
    int v = (t < NBLK_SCAN) ? bsum[t] : 0;
    sm[t] = v;
    __syncthreads();
    for (int off = 1; off < 256; off <<= 1){
        int tv = (t >= off) ? sm[t-off] : 0;
        __syncthreads();
        sm[t] += tv;
        __syncthreads();
    }
    if (t < NBLK_SCAN) bsum[t] = sm[t] - v;   // exclusive
}
__global__ __launch_bounds__(256) void k_scanfinal(const int* __restrict__ cnt,
                                                   const int* __restrict__ bsum,
                                                   int* __restrict__ offs,
                                                   int* __restrict__ cursor,
                                                   float* __restrict__ dinv){
    __shared__ int sm[256];
    int t = threadIdx.x;
    int i = blockIdx.x*256 + t;
    int v = (i < NNODES) ? cnt[i] : 0;
    sm[t] = v;
    __syncthreads();
    for (int off = 1; off < 256; off <<= 1){
        int tv = (t >= off) ? sm[t-off] : 0;
        __syncthreads();
        sm[t] += tv;
        __syncthreads();
    }
    int excl = sm[t] - v + bsum[blockIdx.x];
    if (i < NNODES){
        offs[i] = excl;
        cursor[i] = excl;
        dinv[i] = rsqrtf((float)(v + 1));   // +1 self loop
    }
    if (i == 0) offs[NNODES] = NEDGES;
}
__global__ void k_fill(const int* __restrict__ ei, const float* __restrict__ dinv,
                       int* __restrict__ cursor, int2* __restrict__ csr){
    int e = blockIdx.x*blockDim.x + threadIdx.x;
    if (e < NEDGES){
        int r = ei[e];
        int c = ei[NEDGES + e];
        int pos = atomicAdd(&cursor[c], 1);
        float w = dinv[r]*dinv[c];
        csr[pos] = make_int2(r, __float_as_int(w));
    }
}

// ---------------- GEMM [nrows,128] x [128,128] ----------------
// 128x128 tile, 256 threads, 8x8 microtile.
// rows: r = ty + 16*rr (conflict-free A reads, stride 40)
// cols: j = tx*4 + q*64    (2-way bank alias = free; coalesced stores)
__global__ __launch_bounds__(256) void k_gemm128(const float* __restrict__ A,
                                                 const float* __restrict__ W,
                                                 const float* __restrict__ scale,
                                                 const float* __restrict__ bias,
                                                 int fuse_gelu,
                                                 float* __restrict__ Y){
    __shared__ float As[128*40];
    __shared__ float Ws[32*132];
    int t = threadIdx.x;
    int tx = t & 15;
    int ty = t >> 4;
    int row0 = blockIdx.x * 128;

    float acc[8][8];
    #pragma unroll
    for (int a=0;a<8;a++)
        #pragma unroll
        for (int b=0;b<8;b++) acc[a][b]=0.f;

    for (int k0 = 0; k0 < 128; k0 += 32){
        #pragma unroll
        for (int p=0;p<4;p++){
            int l = p*256 + t;
            int r = l >> 3;       // 0..127
            int c4 = l & 7;       // k chunk
            int gr = row0 + r;
            float4 v = make_float4(0.f,0.f,0.f,0.f);
            if (gr < NNODES) v = *(const float4*)&A[(size_t)gr*FDIM + k0 + c4*4];
            if (scale){
                float4 s = *(const float4*)&scale[k0 + c4*4];
                v.x*=s.x; v.y*=s.y; v.z*=s.z; v.w*=s.w;
            }
            *(float4*)&As[r*40 + c4*4] = v;
        }
        #pragma unroll
        for (int p=0;p<4;p++){
            int l = p*256 + t;
            int kk = l >> 5;
            int j4 = l & 31;
            float4 v = *(const float4*)&W[(size_t)(k0+kk)*FDIM + j4*4];
            *(float4*)&Ws[kk*132 + j4*4] = v;
        }
        __syncthreads();
        #pragma unroll
        for (int kk = 0; kk < 32; kk += 4){
            float4 af[8];
            #pragma unroll
            for (int rr=0;rr<8;rr++){
                int r = ty + 16*rr;
                af[rr] = *(const float4*)&As[r*40 + kk];
            }
            #pragma unroll
            for (int kv=0;kv<4;kv++){
                const float4 w0 = *(const float4*)&Ws[(kk+kv)*132 + tx*4];
                const float4 w1 = *(const float4*)&Ws[(kk+kv)*132 + 64 + tx*4];
                #pragma unroll
                for (int rr=0;rr<8;rr++){
                    const float av = (kv==0) ? af[rr].x : (kv==1) ? af[rr].y :
                                     (kv==2) ? af[rr].z : af[rr].w;
                    acc[rr][0]=fmaf(av,w0.x,acc[rr][0]);
                    acc[rr][1]=fmaf(av,w0.y,acc[rr][1]);
                    acc[rr][2]=fmaf(av,w0.z,acc[rr][2]);
                    acc[rr][3]=fmaf(av,w0.w,acc[rr][3]);
                    acc[rr][4]=fmaf(av,w1.x,acc[rr][4]);
                    acc[rr][5]=fmaf(av,w1.y,acc[rr][5]);
                    acc[rr][6]=fmaf(av,w1.z,acc[rr][6]);
                    acc[rr][7]=fmaf(av,w1.w,acc[rr][7]);
                }
            }
        }
        __syncthreads();
    }
    float4 bv0 = make_float4(0.f,0.f,0.f,0.f), bv1 = bv0;
    if (bias){
        bv0 = *(const float4*)&bias[tx*4];
        bv1 = *(const float4*)&bias[64 + tx*4];
    }
    #pragma unroll
    for (int rr=0;rr<8;rr++){
        int row = row0 + ty + 16*rr;
        if (row < NNODES){
            float4 v0, v1;
            v0.x=acc[rr][0]+bv0.x; v0.y=acc[rr][1]+bv0.y; v0.z=acc[rr][2]+bv0.z; v0.w=acc[rr][3]+bv0.w;
            v1.x=acc[rr][4]+bv1.x; v1.y=acc[rr][5]+bv1.y; v1.z=acc[rr][6]+bv1.z; v1.w=acc[rr][7]+bv1.w;
            if (fuse_gelu){
                v0.x=gelu_erf(v0.x); v0.y=gelu_erf(v0.y); v0.z=gelu_erf(v0.z); v0.w=gelu_erf(v0.w);
                v1.x=gelu_erf(v1.x); v1.y=gelu_erf(v1.y); v1.z=gelu_erf(v1.z); v1.w=gelu_erf(v1.w);
            }
            *(float4*)&Y[(size_t)row*FDIM + tx*4] = v0;
            *(float4*)&Y[(size_t)row*FDIM + 64 + tx*4] = v1;
        }
    }
}

// ---------------- fused aggregation: self-loop + gather + bias + gelu ----------------
__global__ __launch_bounds__(256) void k_aggregate(const float* __restrict__ Y,
                                                   const float* __restrict__ dinv,
                                                   const int* __restrict__ offs,
                                                   const int2* __restrict__ csr,
                                                   const float* __restrict__ bias,
                                                   float* __restrict__ Hout){
    int node = blockIdx.x*4 + (threadIdx.x >> 6);
    int lane = threadIdx.x & 63;
    const float2* Y2 = (const float2*)Y;
    float di = dinv[node];
    float2 y0 = Y2[node*64 + lane];
    float2 acc;
    acc.x = di*di*y0.x;
    acc.y = di*di*y0.y;
    int e0 = offs[node], e1 = offs[node+1];
    int e = e0;
    for (; e + 3 < e1; e += 4){
        int2 p0 = csr[e+0];
        int2 p1 = csr[e+1];
        int2 p2 = csr[e+2];
        int2 p3 = csr[e+3];
        float2 a0 = Y2[p0.x*64 + lane];
        float2 a1 = Y2[p1.x*64 + lane];
        float2 a2 = Y2[p2.x*64 + lane];
        float2 a3 = Y2[p3.x*64 + lane];
        float w0 = __int_as_float(p0.y);
        float w1 = __int_as_float(p1.y);
        float w2 = __int_as_float(p2.y);
        float w3 = __int_as_float(p3.y);
        acc.x = fmaf(w0, a0.x, acc.x);  acc.y = fmaf(w0, a0.y, acc.y);
        acc.x = fmaf(w1, a1.x, acc.x);  acc.y = fmaf(w1, a1.y, acc.y);
        acc.x = fmaf(w2, a2.x, acc.x);  acc.y = fmaf(w2, a2.y, acc.y);
        acc.x = fmaf(w3, a3.x, acc.x);  acc.y = fmaf(w3, a3.y, acc.y);
    }
    for (; e < e1; e++){
        int2 p = csr[e];
        float w = __int_as_float(p.y);
        float2 a = Y2[p.x*64 + lane];
        acc.x = fmaf(w, a.x, acc.x);
        acc.y = fmaf(w, a.y, acc.y);
    }
    float2 bv = ((const float2*)bias)[lane];
    acc.x = gelu_erf(acc.x + bv.x);
    acc.y = gelu_erf(acc.y + bv.y);
    ((float2*)Hout)[node*64 + lane] = acc;
}

// ---------------- final GEMM [nrows,128] x [128,16] + bias ----------------
__global__ __launch_bounds__(256) void k_gemm16(const float* __restrict__ A,
                                                const float* __restrict__ W,
                                                const float* __restrict__ bias,
                                                float* __restrict__ out){
    __shared__ float Hs[16][132];
    __shared__ float Ws2[128][16];
    int row0 = blockIdx.x * 16;
    int t = threadIdx.x;
    #pragma unroll
    for (int p=0;p<8;p++){
        int lin = p*256 + t;
        int r = lin >> 7, c = lin & 127;
        Hs[r][c] = A[(row0+r)*FDIM + c];
    }
    #pragma unroll
    for (int p=0;p<8;p++){
        int lin = p*256 + t;
        Ws2[lin>>4][lin&15] = W[lin];
    }
    __syncthreads();
    int il = t >> 4, j = t & 15;
    float acc = bias[j];
    #pragma unroll
    for (int k=0;k<FDIM;k++) acc = fmaf(Hs[il][k], Ws2[k][j], acc);
    out[(row0+il)*16 + j] = acc;
}

extern "C" void kernel_launch(void* const* d_in, const int* in_sizes, int n_in,
                              void* d_out, int out_size, void* d_ws, size_t ws_size,
                              hipStream_t stream) {
    const float* x    = (const float*)d_in[0];
    const int*   ei   = (const int*)d_in[1];
    const float* imp  = (const float*)d_in[2];
    const float* W1   = (const float*)d_in[3];
    const float* b1   = (const float*)d_in[4];
    const float* W2   = (const float*)d_in[5];
    const float* b2   = (const float*)d_in[6];
    const float* W3   = (const float*)d_in[7];
    const float* b3   = (const float*)d_in[8];
    const float* lw1  = (const float*)d_in[9];
    const float* lb1  = (const float*)d_in[10];
    const float* lw2  = (const float*)d_in[11];
    const float* lb2  = (const float*)d_in[12];
    float* out = (float*)d_out;

    // workspace layout (units of 4 bytes)
    int*   cnt    = (int*)d_ws;                         // 50000
    int*   offs   = (int*)d_ws + 50176;                 // 50001
    int*   cursor = (int*)d_ws + 100480;                // 50000
    int*   bsum   = (int*)d_ws + 150528;                // 256
    float* dinv   = (float*)d_ws + 150784;              // 50000
    int2*  csr    = (int2*)((int*)d_ws + 200960);       // 800000 int2
    float* bufH   = (float*)d_ws + 1800960;             // N*128
    float* bufY   = (float*)d_ws + 8200960;             // N*128

    dim3 B(256);
    // ---- CSR build ----
    k_zero_cnt  <<<NBLK_SCAN, B, 0, stream>>>(cnt);
    k_hist      <<<(NEDGES+255)/256, B, 0, stream>>>(ei, cnt);
    k_blocksum  <<<NBLK_SCAN, B, 0, stream>>>(cnt, bsum);
    k_scanblocks<<<1, B, 0, stream>>>(bsum);
    k_scanfinal <<<NBLK_SCAN, B, 0, stream>>>(cnt, bsum, offs, cursor, dinv);
    k_fill      <<<(NEDGES+255)/256, B, 0, stream>>>(ei, dinv, cursor, csr);

    const int GGRID = (NNODES + 127) / 128;
    const float* Wl[3] = {W1, W2, W3};
    const float* bl[3] = {b1, b2, b3};
    for (int l = 0; l < 3; l++){
        const float* Ain = (l == 0) ? x : bufH;
        const float* sc  = (l == 0) ? imp : nullptr;
        k_gemm128  <<<GGRID, B, 0, stream>>>(Ain, Wl[l], sc, nullptr, 0, bufY);
        k_aggregate<<<(NNODES+3)/4, B, 0, stream>>>(bufY, dinv, offs, csr, bl[l], bufH);
    }
    // h = gelu(h @ lw1 + lb1)
    k_gemm128<<<GGRID, B, 0, stream>>>(bufH, lw1, nullptr, lb1, 1, bufY);
    // out = h @ lw2 + lb2
    k_gemm16 <<<NNODES/16, B, 0, stream>>>(bufY, lw2, lb2, out);
}

// Round 4
// 422.155 us; speedup vs baseline: 10.3256x; 1.1839x over previous
//
#include <hip/hip_runtime.h>
#include <math.h>

#define NNODES 50000
#define NEDGES 800000
#define FDIM 128
#define NBLK_SCAN 196   // ceil(50000/256)

typedef unsigned short ushortT;
typedef unsigned int uintT;

__device__ __forceinline__ float gelu_erf(float x){
    return 0.5f * x * (1.0f + erff(x * 0.70710678118654752f));
}
// bf16 helpers: packed ushort2 in a uint
__device__ __forceinline__ float bflo(uintT u){ return __uint_as_float(u << 16); }
__device__ __forceinline__ float bfhi(uintT u){ return __uint_as_float(u & 0xFFFF0000u); }
__device__ __forceinline__ ushortT f2bf(float f){
    uintT u = __float_as_uint(f);
    return (ushortT)((u + 0x7FFFu + ((u >> 16) & 1u)) >> 16);   // RNE
}

// ---------------- CSR build ----------------
__global__ void k_zero_cnt(int* __restrict__ cnt){
    int i = blockIdx.x*blockDim.x + threadIdx.x;
    if (i < NNODES) cnt[i] = 0;
}
__global__ void k_hist(const int* __restrict__ ei, int* __restrict__ cnt){
    int e = blockIdx.x*blockDim.x + threadIdx.x;
    if (e < NEDGES) atomicAdd(&cnt[ei[NEDGES + e]], 1);
}
__global__ __launch_bounds__(256) void k_blocksum(const int* __restrict__ cnt, int* __restrict__ bsum){
    __shared__ int sm[256];
    int t = threadIdx.x;
    int i = blockIdx.x*256 + t;
    sm[t] = (i < NNODES) ? cnt[i] : 0;
    __syncthreads();
    for (int off = 128; off > 0; off >>= 1){
        if (t < off) sm[t] += sm[t+off];
        __syncthreads();
    }
    if (t == 0) bsum[blockIdx.x] = sm[0];
}
__global__ __launch_bounds__(256) void k_scanblocks(int* __restrict__ bsum){
    __shared__ int sm[256];
    int t = threadIdx.x;
    int v = (t < NBLK_SCAN) ? bsum[t] : 0;
    sm[t] = v;
    __syncthreads();
    for (int off = 1; off < 256; off <<= 1){
        int tv = (t >= off) ? sm[t-off] : 0;
        __syncthreads();
        sm[t] += tv;
        __syncthreads();
    }
    if (t < NBLK_SCAN) bsum[t] = sm[t] - v;   // exclusive
}
__global__ __launch_bounds__(256) void k_scanfinal(const int* __restrict__ cnt,
                                                   const int* __restrict__ bsum,
                                                   int* __restrict__ offs,
                                                   int* __restrict__ cursor,
                                                   float* __restrict__ dinv){
    __shared__ int sm[256];
    int t = threadIdx.x;
    int i = blockIdx.x*256 + t;
    int v = (i < NNODES) ? cnt[i] : 0;
    sm[t] = v;
    __syncthreads();
    for (int off = 1; off < 256; off <<= 1){
        int tv = (t >= off) ? sm[t-off] : 0;
        __syncthreads();
        sm[t] += tv;
        __syncthreads();
    }
    int excl = sm[t] - v + bsum[blockIdx.x];
    if (i < NNODES){
        offs[i] = excl;
        cursor[i] = excl;
        dinv[i] = rsqrtf((float)(v + 1));   // +1 self loop
    }
    if (i == 0) offs[NNODES] = NEDGES;
}
__global__ void k_fill(const int* __restrict__ ei, const float* __restrict__ dinv,
                       int* __restrict__ cursor, int2* __restrict__ csr){
    int e = blockIdx.x*blockDim.x + threadIdx.x;
    if (e < NEDGES){
        int r = ei[e];
        int c = ei[NEDGES + e];
        int pos = atomicAdd(&cursor[c], 1);
        float w = dinv[r]*dinv[c];
        csr[pos] = make_int2(r, __float_as_int(w));
    }
}

// ---------------- GEMM [nrows,128] x [128,128] ----------------
// 128x128 tile, 256 threads, 8x8 microtile. BF16OUT stores Y as bf16.
template<bool BF16OUT>
__global__ __launch_bounds__(256) void k_gemm128(const float* __restrict__ A,
                                                 const float* __restrict__ W,
                                                 const float* __restrict__ scale,
                                                 const float* __restrict__ bias,
                                                 int fuse_gelu,
                                                 void* __restrict__ Yout){
    __shared__ float As[128*40];
    __shared__ float Ws[32*132];
    int t = threadIdx.x;
    int tx = t & 15;
    int ty = t >> 4;
    int row0 = blockIdx.x * 128;

    float acc[8][8];
    #pragma unroll
    for (int a=0;a<8;a++)
        #pragma unroll
        for (int b=0;b<8;b++) acc[a][b]=0.f;

    for (int k0 = 0; k0 < 128; k0 += 32){
        #pragma unroll
        for (int p=0;p<4;p++){
            int l = p*256 + t;
            int r = l >> 3;       // 0..127
            int c4 = l & 7;       // k chunk
            int gr = row0 + r;
            float4 v = make_float4(0.f,0.f,0.f,0.f);
            if (gr < NNODES) v = *(const float4*)&A[(size_t)gr*FDIM + k0 + c4*4];
            if (scale){
                float4 s = *(const float4*)&scale[k0 + c4*4];
                v.x*=s.x; v.y*=s.y; v.z*=s.z; v.w*=s.w;
            }
            *(float4*)&As[r*40 + c4*4] = v;
        }
        #pragma unroll
        for (int p=0;p<4;p++){
            int l = p*256 + t;
            int kk = l >> 5;
            int j4 = l & 31;
            float4 v = *(const float4*)&W[(size_t)(k0+kk)*FDIM + j4*4];
            *(float4*)&Ws[kk*132 + j4*4] = v;
        }
        __syncthreads();
        #pragma unroll
        for (int kk = 0; kk < 32; kk += 4){
            float4 af[8];
            #pragma unroll
            for (int rr=0;rr<8;rr++){
                int r = ty + 16*rr;
                af[rr] = *(const float4*)&As[r*40 + kk];
            }
            #pragma unroll
            for (int kv=0;kv<4;kv++){
                const float4 w0 = *(const float4*)&Ws[(kk+kv)*132 + tx*4];
                const float4 w1 = *(const float4*)&Ws[(kk+kv)*132 + 64 + tx*4];
                #pragma unroll
                for (int rr=0;rr<8;rr++){
                    const float av = (kv==0) ? af[rr].x : (kv==1) ? af[rr].y :
                                     (kv==2) ? af[rr].z : af[rr].w;
                    acc[rr][0]=fmaf(av,w0.x,acc[rr][0]);
                    acc[rr][1]=fmaf(av,w0.y,acc[rr][1]);
                    acc[rr][2]=fmaf(av,w0.z,acc[rr][2]);
                    acc[rr][3]=fmaf(av,w0.w,acc[rr][3]);
                    acc[rr][4]=fmaf(av,w1.x,acc[rr][4]);
                    acc[rr][5]=fmaf(av,w1.y,acc[rr][5]);
                    acc[rr][6]=fmaf(av,w1.z,acc[rr][6]);
                    acc[rr][7]=fmaf(av,w1.w,acc[rr][7]);
                }
            }
        }
        __syncthreads();
    }
    float4 bv0 = make_float4(0.f,0.f,0.f,0.f), bv1 = bv0;
    if (bias){
        bv0 = *(const float4*)&bias[tx*4];
        bv1 = *(const float4*)&bias[64 + tx*4];
    }
    #pragma unroll
    for (int rr=0;rr<8;rr++){
        int row = row0 + ty + 16*rr;
        if (row < NNODES){
            float4 v0, v1;
            v0.x=acc[rr][0]+bv0.x; v0.y=acc[rr][1]+bv0.y; v0.z=acc[rr][2]+bv0.z; v0.w=acc[rr][3]+bv0.w;
            v1.x=acc[rr][4]+bv1.x; v1.y=acc[rr][5]+bv1.y; v1.z=acc[rr][6]+bv1.z; v1.w=acc[rr][7]+bv1.w;
            if (fuse_gelu){
                v0.x=gelu_erf(v0.x); v0.y=gelu_erf(v0.y); v0.z=gelu_erf(v0.z); v0.w=gelu_erf(v0.w);
                v1.x=gelu_erf(v1.x); v1.y=gelu_erf(v1.y); v1.z=gelu_erf(v1.z); v1.w=gelu_erf(v1.w);
            }
            if (BF16OUT){
                ushortT* Yb = (ushortT*)Yout;
                ushort4 o0, o1;
                o0.x=f2bf(v0.x); o0.y=f2bf(v0.y); o0.z=f2bf(v0.z); o0.w=f2bf(v0.w);
                o1.x=f2bf(v1.x); o1.y=f2bf(v1.y); o1.z=f2bf(v1.z); o1.w=f2bf(v1.w);
                *(ushort4*)&Yb[(size_t)row*FDIM + tx*4] = o0;
                *(ushort4*)&Yb[(size_t)row*FDIM + 64 + tx*4] = o1;
            } else {
                float* Yf = (float*)Yout;
                *(float4*)&Yf[(size_t)row*FDIM + tx*4] = v0;
                *(float4*)&Yf[(size_t)row*FDIM + 64 + tx*4] = v1;
            }
        }
    }
}

// ---------------- fused aggregation (bf16 Y): self-loop + gather + bias + gelu ----
// One wave per node; lane handles 2 features packed as bf16x2 (uint).
__global__ __launch_bounds__(256) void k_aggregate(const ushortT* __restrict__ Y,
                                                   const float* __restrict__ dinv,
                                                   const int* __restrict__ offs,
                                                   const int2* __restrict__ csr,
                                                   const float* __restrict__ bias,
                                                   float* __restrict__ Hout){
    int node = blockIdx.x*4 + (threadIdx.x >> 6);
    int lane = threadIdx.x & 63;
    const uintT* Y2 = (const uintT*)Y;
    float di = dinv[node];
    float s = di*di;
    uintT y0 = Y2[node*64 + lane];
    float2 acc;
    acc.x = s * bflo(y0);
    acc.y = s * bfhi(y0);
    int e0 = offs[node], e1 = offs[node+1];
    int e = e0;
    for (; e + 7 < e1; e += 8){
        int2 p[8]; uintT a[8];
        #pragma unroll
        for (int q=0;q<8;q++) p[q] = csr[e+q];
        #pragma unroll
        for (int q=0;q<8;q++) a[q] = Y2[p[q].x*64 + lane];
        #pragma unroll
        for (int q=0;q<8;q++){
            float w = __int_as_float(p[q].y);
            acc.x = fmaf(w, bflo(a[q]), acc.x);
            acc.y = fmaf(w, bfhi(a[q]), acc.y);
        }
    }
    for (; e + 1 < e1; e += 2){
        int2 p0 = csr[e], p1 = csr[e+1];
        uintT a0 = Y2[p0.x*64 + lane];
        uintT a1 = Y2[p1.x*64 + lane];
        float w0 = __int_as_float(p0.y);
        float w1 = __int_as_float(p1.y);
        acc.x = fmaf(w0, bflo(a0), acc.x);
        acc.y = fmaf(w0, bfhi(a0), acc.y);
        acc.x = fmaf(w1, bflo(a1), acc.x);
        acc.y = fmaf(w1, bfhi(a1), acc.y);
    }
    if (e < e1){
        int2 p = csr[e];
        uintT a = Y2[p.x*64 + lane];
        float w = __int_as_float(p.y);
        acc.x = fmaf(w, bflo(a), acc.x);
        acc.y = fmaf(w, bfhi(a), acc.y);
    }
    float2 bv = ((const float2*)bias)[lane];
    acc.x = gelu_erf(acc.x + bv.x);
    acc.y = gelu_erf(acc.y + bv.y);
    ((float2*)Hout)[node*64 + lane] = acc;
}

// ---------------- final GEMM [nrows,128] x [128,16] + bias ----------------
__global__ __launch_bounds__(256) void k_gemm16(const float* __restrict__ A,
                                                const float* __restrict__ W,
                                                const float* __restrict__ bias,
                                                float* __restrict__ out){
    __shared__ float Hs[16][132];
    __shared__ float Ws2[128][16];
    int row0 = blockIdx.x * 16;
    int t = threadIdx.x;
    #pragma unroll
    for (int p=0;p<8;p++){
        int lin = p*256 + t;
        int r = lin >> 7, c = lin & 127;
        Hs[r][c] = A[(row0+r)*FDIM + c];
    }
    #pragma unroll
    for (int p=0;p<8;p++){
        int lin = p*256 + t;
        Ws2[lin>>4][lin&15] = W[lin];
    }
    __syncthreads();
    int il = t >> 4, j = t & 15;
    float acc = bias[j];
    #pragma unroll
    for (int k=0;k<FDIM;k++) acc = fmaf(Hs[il][k], Ws2[k][j], acc);
    out[(row0+il)*16 + j] = acc;
}

extern "C" void kernel_launch(void* const* d_in, const int* in_sizes, int n_in,
                              void* d_out, int out_size, void* d_ws, size_t ws_size,
                              hipStream_t stream) {
    const float* x    = (const float*)d_in[0];
    const int*   ei   = (const int*)d_in[1];
    const float* imp  = (const float*)d_in[2];
    const float* W1   = (const float*)d_in[3];
    const float* b1   = (const float*)d_in[4];
    const float* W2   = (const float*)d_in[5];
    const float* b2   = (const float*)d_in[6];
    const float* W3   = (const float*)d_in[7];
    const float* b3   = (const float*)d_in[8];
    const float* lw1  = (const float*)d_in[9];
    const float* lb1  = (const float*)d_in[10];
    const float* lw2  = (const float*)d_in[11];
    const float* lb2  = (const float*)d_in[12];
    float* out = (float*)d_out;

    // workspace layout (units of 4 bytes)
    int*   cnt    = (int*)d_ws;                         // 50000
    int*   offs   = (int*)d_ws + 50176;                 // 50001
    int*   cursor = (int*)d_ws + 100480;                // 50000
    int*   bsum   = (int*)d_ws + 150528;                // 256
    float* dinv   = (float*)d_ws + 150784;              // 50000
    int2*  csr    = (int2*)((int*)d_ws + 200960);       // 800000 int2
    float* bufH   = (float*)d_ws + 1800960;             // N*128 fp32
    float* bufY   = (float*)d_ws + 8200960;             // N*128 fp32 (layer-4 only)
    ushortT* bufYb = (ushortT*)bufY;                    // alias: bf16 Y for conv layers

    dim3 B(256);
    // ---- CSR build ----
    k_zero_cnt  <<<NBLK_SCAN, B, 0, stream>>>(cnt);
    k_hist      <<<(NEDGES+255)/256, B, 0, stream>>>(ei, cnt);
    k_blocksum  <<<NBLK_SCAN, B, 0, stream>>>(cnt, bsum);
    k_scanblocks<<<1, B, 0, stream>>>(bsum);
    k_scanfinal <<<NBLK_SCAN, B, 0, stream>>>(cnt, bsum, offs, cursor, dinv);
    k_fill      <<<(NEDGES+255)/256, B, 0, stream>>>(ei, dinv, cursor, csr);

    const int GGRID = (NNODES + 127) / 128;
    const float* Wl[3] = {W1, W2, W3};
    const float* bl[3] = {b1, b2, b3};
    for (int l = 0; l < 3; l++){
        const float* Ain = (l == 0) ? x : bufH;
        const float* sc  = (l == 0) ? imp : nullptr;
        k_gemm128<true><<<GGRID, B, 0, stream>>>(Ain, Wl[l], sc, nullptr, 0, (void*)bufYb);
        k_aggregate<<<(NNODES+3)/4, B, 0, stream>>>(bufYb, dinv, offs, csr, bl[l], bufH);
    }
    // h = gelu(h @ lw1 + lb1)
    k_gemm128<false><<<GGRID, B, 0, stream>>>(bufH, lw1, nullptr, lb1, 1, (void*)bufY);
    // out = h @ lw2 + lb2
    k_gemm16<<<NNODES/16, B, 0, stream>>>(bufY, lw2, lb2, out);
}